// Round 8
// baseline (61.611 us; speedup 1.0000x reference)
//
#include <hip/hip_runtime.h>
#include <hip/hip_bf16.h>

// ROUND 8 = MEASUREMENT PROBE, intentionally slower:
// gemm launched 5x (idempotent) to measure per-gemm cost:
//   dur - 23.26us = 4*(gemm_exec + node_overhead)
// Kernels are byte-identical to R7.

#define BB 4096
#define CC 256
#define DD 512
#define SS 8

#define BM 64
#define BN 64
#define BK 64

typedef __attribute__((ext_vector_type(4))) float f32x4;
typedef __attribute__((ext_vector_type(8))) short s16x8;

// float -> bf16 bits, RNE via HW cvt
static __device__ inline short f2bf(float f) {
    __hip_bfloat16 h = __float2bfloat16(f);
    return *reinterpret_cast<short*>(&h);
}

// ws layout:
//   meta[0..7]  : per-subject counts
//   meta[8..15] : per-subject exclusive offsets
//   rows[4096]  : compacted row indices, grouped by subject
//   w_bf        : [s][kb=32][n=512][8] bf16
__global__ __launch_bounds__(256) void prep_kernel(
    const float* __restrict__ w, const int* __restrict__ subj,
    int* __restrict__ meta, int* __restrict__ rows, short* __restrict__ w_bf)
{
    const int tid = threadIdx.x;
    if (blockIdx.x == 0) {
        __shared__ int hist[SS], cur[SS];
        const int lane = tid & 63;
        const unsigned long long lt = (1ull << lane) - 1ull;
        if (tid < SS) hist[tid] = 0;
        __syncthreads();
        int sl[16];
#pragma unroll
        for (int i = 0; i < 16; ++i) sl[i] = subj[tid + i * 256];
#pragma unroll
        for (int i = 0; i < 16; ++i) {
            int s = sl[i];
            unsigned long long same = 0;
#pragma unroll
            for (int v = 0; v < SS; ++v) {
                unsigned long long mv = __ballot(s == v);
                if (s == v) same = mv;
            }
            int leader = __builtin_ctzll(same);
            if (lane == leader) atomicAdd(&hist[s], __popcll(same));
        }
        __syncthreads();
        if (tid == 0) {
            int o = 0;
            for (int v = 0; v < SS; ++v) {
                int c = hist[v];
                meta[v] = c; meta[SS + v] = o; cur[v] = o; o += c;
            }
        }
        __syncthreads();
#pragma unroll
        for (int i = 0; i < 16; ++i) {
            int s = sl[i];
            unsigned long long same = 0;
#pragma unroll
            for (int v = 0; v < SS; ++v) {
                unsigned long long mv = __ballot(s == v);
                if (s == v) same = mv;
            }
            int leader = __builtin_ctzll(same);
            int rank = __popcll(same & lt);
            int base = 0;
            if (lane == leader) base = atomicAdd(&cur[s], __popcll(same));
            base = __shfl(base, leader);
            rows[base + rank] = tid + i * 256;
        }
    } else if (blockIdx.x >= 8) {
        int j = blockIdx.x - 8;                // [0, 512)
        int s = j & 7, c = j >> 3;             // chunk c in [0,64)
        int ul = c * 256 + tid;                // [0, 16384) within subject
        int n = ul & 511, kb = ul >> 9;
        const float* wp = w + ((size_t)(s * CC + kb * 8)) * DD + n;
        s16x8 p;
#pragma unroll
        for (int e = 0; e < 8; ++e) p[e] = f2bf(wp[(size_t)e * DD]);
        *reinterpret_cast<s16x8*>(w_bf + ((size_t)s * 16384 + ul) * 8) = p;
    }
}

// gemm grid = 1024 flat: s = bid&7 (XCD affinity), rt = (bid>>3)&15, ct = bid>>7
__global__ __launch_bounds__(256) void gemm_kernel(
    const float* __restrict__ x, const short* __restrict__ w_bf,
    const float* __restrict__ bias, const int* __restrict__ meta,
    const int* __restrict__ rows, float* __restrict__ out)
{
    const int s  = blockIdx.x & 7;
    const int rt = (blockIdx.x >> 3) & 15;
    const int ct = blockIdx.x >> 7;
    const int n_s = meta[s];
    if (rt * BM >= n_s) return;
    const int off = meta[SS + s];
    int m_valid = n_s - rt * BM; if (m_valid > BM) m_valid = BM;

    __shared__ __align__(16) short As[2][BM * BK];
    __shared__ __align__(16) short Bs[2][BK / 8][BN][8];
    __shared__ int rows_l[BM];

    const int tid = threadIdx.x;
    if (tid < BM) {
        int idx = rt * BM + tid;
        rows_l[tid] = (idx < n_s) ? rows[off + idx] : -1;
    }
    __syncthreads();

    const int bcol = ct * BN;
    const int lane = tid & 63, wid = tid >> 6;
    const int wm = wid & 1, wn = wid >> 1;
    const int lr = lane & 15, lg = lane >> 4;

    f32x4 acc[2][2];
#pragma unroll
    for (int mf = 0; mf < 2; ++mf)
#pragma unroll
        for (int nf = 0; nf < 2; ++nf)
            acc[mf][nf] = (f32x4)0.0f;

    const int ar = tid >> 2;
    const int grow = rows_l[ar];
    const float* xp = x + (size_t)(grow < 0 ? 0 : grow) * CC + (tid & 3) * 16;
    const short* wsrc = w_bf + ((size_t)(s * 32) * 512 + bcol) * 8;

    f32x4 xa[4];
    s16x8 wv2[2];

    auto LOADS = [&](int ks) {
        if (grow >= 0) {
#pragma unroll
            for (int i = 0; i < 4; ++i)
                xa[i] = *reinterpret_cast<const f32x4*>(xp + ks * BK + i * 4);
        } else {
#pragma unroll
            for (int i = 0; i < 4; ++i) xa[i] = (f32x4)0.0f;
        }
#pragma unroll
        for (int i = 0; i < 2; ++i) {
            int ch = tid + i * 256;
            int kb = ch >> 6, nn = ch & 63;
            wv2[i] = *reinterpret_cast<const s16x8*>(
                wsrc + ((size_t)(ks * 8 + kb) * 512 + nn) * 8);
        }
    };
    auto STORE = [&](int pb) {
#pragma unroll
        for (int i = 0; i < 2; ++i) {
            s16x8 p;
            p[0] = f2bf(xa[2 * i][0]); p[1] = f2bf(xa[2 * i][1]);
            p[2] = f2bf(xa[2 * i][2]); p[3] = f2bf(xa[2 * i][3]);
            p[4] = f2bf(xa[2 * i + 1][0]); p[5] = f2bf(xa[2 * i + 1][1]);
            p[6] = f2bf(xa[2 * i + 1][2]); p[7] = f2bf(xa[2 * i + 1][3]);
            int c = (tid & 3) * 2 + i;
            *reinterpret_cast<s16x8*>(reinterpret_cast<char*>(As[pb])
                + ar * 128 + ((c * 16) ^ ((ar & 7) << 4))) = p;
        }
#pragma unroll
        for (int i = 0; i < 2; ++i) {
            int ch = tid + i * 256;
            int kb = ch >> 6, nn = ch & 63;
            *reinterpret_cast<s16x8*>(&Bs[pb][kb][nn][0]) = wv2[i];
        }
    };
    auto COMPUTE = [&](int pb) {
        s16x8 af[2][2], bfr[2][2];
#pragma unroll
        for (int mf = 0; mf < 2; ++mf) {
            int row = wm * 32 + mf * 16 + lr;
#pragma unroll
            for (int kh = 0; kh < 2; ++kh) {
                int kf2 = (kh * 32 + lg * 8) * 2;
                af[mf][kh] = *reinterpret_cast<s16x8*>(reinterpret_cast<char*>(As[pb])
                    + row * 128 + (kf2 ^ ((row & 7) << 4)));
            }
        }
#pragma unroll
        for (int nf = 0; nf < 2; ++nf) {
            int n = wn * 32 + nf * 16 + lr;
#pragma unroll
            for (int kh = 0; kh < 2; ++kh)
                bfr[nf][kh] = *reinterpret_cast<s16x8*>(&Bs[pb][kh * 4 + lg][n][0]);
        }
#pragma unroll
        for (int mf = 0; mf < 2; ++mf)
#pragma unroll
            for (int nf = 0; nf < 2; ++nf)
#pragma unroll
                for (int kh = 0; kh < 2; ++kh)
                    acc[mf][nf] = __builtin_amdgcn_mfma_f32_16x16x32_bf16(
                        af[mf][kh], bfr[nf][kh], acc[mf][nf], 0, 0, 0);
    };

    LOADS(0);
    STORE(0);
    __syncthreads();
#pragma unroll
    for (int ks = 0; ks < CC / BK - 1; ++ks) {
        LOADS(ks + 1);
        COMPUTE(ks & 1);
        STORE((ks + 1) & 1);
        __syncthreads();
    }
    COMPUTE((CC / BK - 1) & 1);

#pragma unroll
    for (int nf = 0; nf < 2; ++nf) {
        int col = bcol + wn * 32 + nf * 16 + lr;
        float bv = bias[s * DD + col];
#pragma unroll
        for (int mf = 0; mf < 2; ++mf) {
            int rl0 = wm * 32 + mf * 16 + lg * 4;
#pragma unroll
            for (int r = 0; r < 4; ++r) {
                int rl = rl0 + r;
                if (rl < m_valid) {
                    int g = rows_l[rl];
                    out[(size_t)g * DD + col] = acc[mf][nf][r] + bv;
                }
            }
        }
    }
}

extern "C" void kernel_launch(void* const* d_in, const int* in_sizes, int n_in,
                              void* d_out, int out_size, void* d_ws, size_t ws_size,
                              hipStream_t stream) {
    const float* x        = (const float*)d_in[0];
    const int*   subjects = (const int*)d_in[1];
    const float* weights  = (const float*)d_in[2];
    const float* bias     = (const float*)d_in[3];
    float* out = (float*)d_out;

    int* meta  = (int*)d_ws;
    int* rows  = meta + 128;
    short* w_bf = (short*)(rows + BB);          // 2 MB

    prep_kernel<<<520, 256, 0, stream>>>(weights, subjects, meta, rows, w_bf);
    // PROBE: 5 identical (idempotent) gemm launches; delta vs R7 = 4*(g+h)
    for (int rep = 0; rep < 5; ++rep)
        gemm_kernel<<<1024, 256, 0, stream>>>(x, w_bf, bias, meta, rows, out);
}

// Round 10
// 17.865 us; speedup vs baseline: 3.4488x; 3.4488x over previous
//
#include <hip/hip_runtime.h>
#include <hip/hip_bf16.h>

#define BB 4096
#define CC 256
#define DD 512
#define SS 8

#define BM 64
#define BN 64
#define BK 64

typedef __attribute__((ext_vector_type(4))) float f32x4;
typedef __attribute__((ext_vector_type(8))) short s16x8;

// float -> bf16 bits, RNE via HW cvt
static __device__ inline short f2bf(float f) {
    __hip_bfloat16 h = __float2bfloat16(f);
    return *reinterpret_cast<short*>(&h);
}

// Single regular kernel, grid = 1024 flat:
//   s = bid&7 (XCD affinity), rt = (bid>>3)&15, ct = bid>>7
// Order: own-subject binning -> uniform early exit -> dbuf GEMM
// (W read fp32 directly, inline cvt; no workspace, no second node)
__global__ __launch_bounds__(256) void fused_kernel(
    const float* __restrict__ x, const int* __restrict__ subj,
    const float* __restrict__ w, const float* __restrict__ bias,
    float* __restrict__ out)
{
    const int s  = blockIdx.x & 7;
    const int rt = (blockIdx.x >> 3) & 15;
    const int ct = blockIdx.x >> 7;
    const int tid = threadIdx.x;
    const int lane = tid & 63, wv = tid >> 6;
    const unsigned long long lt = (1ull << lane) - 1ull;

    __shared__ __align__(16) short As[2][BM * BK];       // 2 x 8KB, swizzled
    __shared__ __align__(16) short Bs[2][BK / 8][BN][8]; // 2 x 8KB, k-blocked
    __shared__ int wcnt[16][4];                          // own-subject counts
    __shared__ int pre[16][4];                           // exclusive prefix
    __shared__ int rows_l[BM];
    __shared__ int ns_sh;

    if (tid < BM) rows_l[tid] = -1;

    // ---- binning pass 1: own-subject counts per (chunk, wave)
    int sl[16];
#pragma unroll
    for (int i = 0; i < 16; ++i) sl[i] = subj[tid + i * 256];
#pragma unroll
    for (int i = 0; i < 16; ++i) {
        unsigned long long m = __ballot(sl[i] == s);
        if (lane == 0) wcnt[i][wv] = __popcll(m);
    }
    __syncthreads();

    // ---- 64-entry exclusive scan (chunk-major, wave-minor) in wave 0
    if (tid < 64) {
        int c = wcnt[tid >> 2][tid & 3];
        int inc = c;
#pragma unroll
        for (int d2 = 1; d2 < 64; d2 <<= 1) {
            int o = __shfl_up(inc, d2, 64);
            if (lane >= d2) inc += o;
        }
        pre[tid >> 2][tid & 3] = inc - c;
        if (tid == 63) ns_sh = inc;
    }
    __syncthreads();

    const int n_s = ns_sh;
    if (rt * BM >= n_s) return;                          // uniform early exit
    int m_valid = n_s - rt * BM; if (m_valid > BM) m_valid = BM;

    // ---- binning pass 2: place this tile's rows
#pragma unroll
    for (int i = 0; i < 16; ++i) {
        unsigned long long m = __ballot(sl[i] == s);
        if (sl[i] == s) {
            int rank = pre[i][wv] + __popcll(m & lt);
            int p = rank - rt * BM;
            if (p >= 0 && p < BM) rows_l[p] = tid + i * 256;
        }
    }
    __syncthreads();

    // ---- GEMM (R7 dbuf body; B staged from fp32 W with inline cvt)
    const int wm = wv & 1, wn = wv >> 1;
    const int lr = lane & 15, lg = lane >> 4;

    f32x4 acc[2][2];
#pragma unroll
    for (int mf = 0; mf < 2; ++mf)
#pragma unroll
        for (int nf = 0; nf < 2; ++nf)
            acc[mf][nf] = (f32x4)0.0f;

    const int ar = tid >> 2;                   // A row (4 threads/row)
    const int grow = rows_l[ar];
    const float* xp = x + (size_t)(grow < 0 ? 0 : grow) * CC + (tid & 3) * 16;
    const float* wb = w + (size_t)s * CC * DD + ct * BN + lane;  // column = lane

    f32x4 xa[4];                               // next A chunk (16 floats)
    float wf[2][8];                            // next B chunks (2 kb x 8 k)

    auto LOADS = [&](int ks) {
        if (grow >= 0) {
#pragma unroll
            for (int i = 0; i < 4; ++i)
                xa[i] = *reinterpret_cast<const f32x4*>(xp + ks * BK + i * 4);
        } else {
#pragma unroll
            for (int i = 0; i < 4; ++i) xa[i] = (f32x4)0.0f;
        }
#pragma unroll
        for (int i = 0; i < 2; ++i) {
            int kb = wv + i * 4;
#pragma unroll
            for (int e = 0; e < 8; ++e)
                wf[i][e] = wb[(size_t)(ks * BK + kb * 8 + e) * DD];
        }
    };
    auto STORE = [&](int pb) {
#pragma unroll
        for (int i = 0; i < 2; ++i) {
            s16x8 p;
            p[0] = f2bf(xa[2 * i][0]); p[1] = f2bf(xa[2 * i][1]);
            p[2] = f2bf(xa[2 * i][2]); p[3] = f2bf(xa[2 * i][3]);
            p[4] = f2bf(xa[2 * i + 1][0]); p[5] = f2bf(xa[2 * i + 1][1]);
            p[6] = f2bf(xa[2 * i + 1][2]); p[7] = f2bf(xa[2 * i + 1][3]);
            int c = (tid & 3) * 2 + i;
            *reinterpret_cast<s16x8*>(reinterpret_cast<char*>(As[pb])
                + ar * 128 + ((c * 16) ^ ((ar & 7) << 4))) = p;
        }
#pragma unroll
        for (int i = 0; i < 2; ++i) {
            s16x8 p;
#pragma unroll
            for (int e = 0; e < 8; ++e) p[e] = f2bf(wf[i][e]);
            *reinterpret_cast<s16x8*>(&Bs[pb][wv + i * 4][lane][0]) = p;
        }
    };
    auto COMPUTE = [&](int pb) {
        s16x8 af[2][2], bfr[2][2];
#pragma unroll
        for (int mf = 0; mf < 2; ++mf) {
            int row = wm * 32 + mf * 16 + lr;
#pragma unroll
            for (int kh = 0; kh < 2; ++kh) {
                int kf2 = (kh * 32 + lg * 8) * 2;
                af[mf][kh] = *reinterpret_cast<s16x8*>(reinterpret_cast<char*>(As[pb])
                    + row * 128 + (kf2 ^ ((row & 7) << 4)));
            }
        }
#pragma unroll
        for (int nf = 0; nf < 2; ++nf) {
            int n = wn * 32 + nf * 16 + lr;
#pragma unroll
            for (int kh = 0; kh < 2; ++kh)
                bfr[nf][kh] = *reinterpret_cast<s16x8*>(&Bs[pb][kh * 4 + lg][n][0]);
        }
#pragma unroll
        for (int mf = 0; mf < 2; ++mf)
#pragma unroll
            for (int nf = 0; nf < 2; ++nf)
#pragma unroll
                for (int kh = 0; kh < 2; ++kh)
                    acc[mf][nf] = __builtin_amdgcn_mfma_f32_16x16x32_bf16(
                        af[mf][kh], bfr[nf][kh], acc[mf][nf], 0, 0, 0);
    };

    LOADS(0);
    STORE(0);
    __syncthreads();
#pragma unroll
    for (int ks = 0; ks < CC / BK - 1; ++ks) {
        LOADS(ks + 1);          // issue next loads early (hide under MFMA)
        COMPUTE(ks & 1);
        STORE((ks + 1) & 1);    // opposite buffer: no pre-write barrier needed
        __syncthreads();
    }
    COMPUTE((CC / BK - 1) & 1);

    // ---- epilogue: + bias, scatter rows back
#pragma unroll
    for (int nf = 0; nf < 2; ++nf) {
        int col = ct * BN + wn * 32 + nf * 16 + lr;
        float bv = bias[s * DD + col];
#pragma unroll
        for (int mf = 0; mf < 2; ++mf) {
            int rl0 = wm * 32 + mf * 16 + lg * 4;
#pragma unroll
            for (int r = 0; r < 4; ++r) {
                int rl = rl0 + r;
                if (rl < m_valid) {
                    int g = rows_l[rl];
                    out[(size_t)g * DD + col] = acc[mf][nf][r] + bv;
                }
            }
        }
    }
}

extern "C" void kernel_launch(void* const* d_in, const int* in_sizes, int n_in,
                              void* d_out, int out_size, void* d_ws, size_t ws_size,
                              hipStream_t stream) {
    const float* x        = (const float*)d_in[0];
    const int*   subjects = (const int*)d_in[1];
    const float* weights  = (const float*)d_in[2];
    const float* bias     = (const float*)d_in[3];
    float* out = (float*)d_out;

    fused_kernel<<<1024, 256, 0, stream>>>(x, subjects, weights, bias, out);
}